// Round 3
// baseline (211.548 us; speedup 1.0000x reference)
//
#include <hip/hip_runtime.h>
#include <hip/hip_bf16.h>

// 2-layer GCN on MI355X.
// R7 post-mortem: block-range fusion FAILED (34KB static LDS allocated for
// build blocks too -> build occupancy halved; fused = serial sum 60us; plus
// 6.4M LDS bank conflicts from in-kernel W1 transpose). Aggregates are ~120us
// of the 195 (random 256B/128B gathers from 12.8/6.4MB arrays -> L3 latency).
// R8: chunk-major feature layout [chunk][N][32] bf16 -> per-pass gather set
// = 3.2MB < 4MB per-XCD L2. Aggregates run as n_chunk separate dispatches
// (dispatch boundary = perfect phase separation). Quarter-wave (16 lanes)
// per 64B row. Gemms write chunk-major; gemm2 reads chunked A natively
// (MFMA K-fragment kk == chunk kk). Build reverted to standalone (8 VGPR,
// no LDS, full occupancy); gemm1 re-scaled by dinv; w1t/w2t in init.

#define ELL_CAP 64   // deg ~ Poisson(16); P(deg>=64) ~ 1e-18
#define NPART 8      // = XCD count

typedef __attribute__((ext_vector_type(8))) short short8;   // 8 bf16 (4 VGPRs)
typedef __attribute__((ext_vector_type(4))) float f32x4;

static __device__ __forceinline__ unsigned short f2bf(float f) {
    unsigned int u = __float_as_uint(f);
    u = (u + 0x7fff + ((u >> 16) & 1)) >> 16;   // round-to-nearest-even
    return (unsigned short)u;
}
static __device__ __forceinline__ float2 bfunpack(unsigned int u) {
    return make_float2(__uint_as_float(u << 16),            // low short  = feat 2i
                       __uint_as_float(u & 0xffff0000u));   // high short = feat 2i+1
}

// ---------------- init: cnt zeroing + both weight transposes ----------------

__global__ void init_misc(const float* __restrict__ W1, const float* __restrict__ W2,
                          short* __restrict__ w1t, short* __restrict__ w2t,
                          int* __restrict__ cnt, int n)
{
    int i = blockIdx.x * blockDim.x + threadIdx.x;
    if (i < 128 * 128) {
        int k = i >> 7, nn = i & 127;
        w1t[nn * 128 + k] = (short)f2bf(W1[i]);
    } else if (i < 128 * 128 + 128 * 64) {
        int j = i - 128 * 128;
        int k = j >> 6, nn = j & 63;
        w2t[nn * 128 + k] = (short)f2bf(W2[j]);
    }
    if (i < n) cnt[i] = 0;
}

// ---------------- XCD-partitioned ELL build (standalone, no LDS) -----------

__global__ __launch_bounds__(256) void build_ell_part(
    const int* __restrict__ src, const int* __restrict__ dst,
    int* __restrict__ cnt, unsigned short* __restrict__ ell, int E, int partSize)
{
    const int part   = blockIdx.x & (NPART - 1);   // = XCD under round-robin
    const int chunk  = blockIdx.x >> 3;
    const int nchunk = gridDim.x >> 3;
    const int lo = part * partSize, hi = lo + partSize;

    const int  E4  = E >> 2;
    const int  per = (E4 + nchunk - 1) / nchunk;
    const int  i1  = min((chunk + 1) * per, E4);
    const int4* __restrict__ d4p = (const int4*)dst;
    const int4* __restrict__ s4p = (const int4*)src;

    for (int i = chunk * per + threadIdx.x; i < i1; i += 256) {
        int4 d4 = d4p[i];
        int4 s4 = s4p[i];
        if (d4.x >= lo && d4.x < hi) {
            int p = atomicAdd(&cnt[d4.x], 1);
            if (p < ELL_CAP) ell[(size_t)d4.x * ELL_CAP + p] = (unsigned short)s4.x;
        }
        if (d4.y >= lo && d4.y < hi) {
            int p = atomicAdd(&cnt[d4.y], 1);
            if (p < ELL_CAP) ell[(size_t)d4.y * ELL_CAP + p] = (unsigned short)s4.y;
        }
        if (d4.z >= lo && d4.z < hi) {
            int p = atomicAdd(&cnt[d4.z], 1);
            if (p < ELL_CAP) ell[(size_t)d4.z * ELL_CAP + p] = (unsigned short)s4.z;
        }
        if (d4.w >= lo && d4.w < hi) {
            int p = atomicAdd(&cnt[d4.w], 1);
            if (p < ELL_CAP) ell[(size_t)d4.w * ELL_CAP + p] = (unsigned short)s4.w;
        }
    }
    if (chunk == 0) {                              // E % 4 tail
        for (int e = (E & ~3) + threadIdx.x; e < E; e += 256) {
            int d = dst[e];
            if (d >= lo && d < hi) {
                int p = atomicAdd(&cnt[d], 1);
                if (p < ELL_CAP) ell[(size_t)d * ELL_CAP + p] = (unsigned short)src[e];
            }
        }
    }
}

// ---------------- MFMA GEMM: C = bf16(dinv[i] * (A W)[i][:]), chunk-major --
// A: AF32 ? fp32 [n][128] row-major (converted in-flight)
//         : chunked bf16 [4][n][32] (z1 layout; chunk kk == K-fragment kk)
// Bt: [NC][128] bf16 (W transposed), C: chunk-major [NC/32][n][32] bf16.
// Block = 64 rows, 4 waves, wave = 16-row strip. n % 16 == 0.

template<int NC, bool AF32>
__global__ __launch_bounds__(256) void gemm_mfma(
    const void* __restrict__ Av, const short* __restrict__ Bt,
    const int* __restrict__ cnt, unsigned short* __restrict__ Cb, int n)
{
    __shared__ short Bs[NC][136];
    const int tid = threadIdx.x;

    #pragma unroll
    for (int i = 0; i < NC / 16; ++i) {      // NC*128 shorts, 16B per thread/iter
        int idx = tid + i * 256;
        int nrow = idx >> 4;
        int kcol = (idx & 15) * 8;
        *(short8*)&Bs[nrow][kcol] = *(const short8*)(Bt + nrow * 128 + kcol);
    }
    __syncthreads();

    const int wave = tid >> 6, lane = tid & 63;
    const int row0 = blockIdx.x * 64 + wave * 16;
    if (row0 >= n) return;
    const int quad = lane >> 4, l16 = lane & 15;

    short8 af[4];
    if (AF32) {
        const float* arow = (const float*)Av + (size_t)(row0 + l16) * 128 + quad * 8;
        #pragma unroll
        for (int kk = 0; kk < 4; ++kk) {
            float4 u = *(const float4*)(arow + kk * 32);
            float4 v = *(const float4*)(arow + kk * 32 + 4);
            short8 f;
            f[0] = (short)f2bf(u.x); f[1] = (short)f2bf(u.y);
            f[2] = (short)f2bf(u.z); f[3] = (short)f2bf(u.w);
            f[4] = (short)f2bf(v.x); f[5] = (short)f2bf(v.y);
            f[6] = (short)f2bf(v.z); f[7] = (short)f2bf(v.w);
            af[kk] = f;
        }
    } else {
        // chunked A: chunk kk at Av + kk*n*32, row stride 32
        #pragma unroll
        for (int kk = 0; kk < 4; ++kk)
            af[kk] = *(const short8*)((const short*)Av + (size_t)kk * n * 32
                                      + (size_t)(row0 + l16) * 32 + quad * 8);
    }

    float dv[4];
    #pragma unroll
    for (int r = 0; r < 4; ++r)
        dv[r] = rsqrtf((float)cnt[row0 + quad * 4 + r] + 1.0f);

    #pragma unroll
    for (int t = 0; t < NC / 16; ++t) {
        f32x4 acc = {0.f, 0.f, 0.f, 0.f};
        #pragma unroll
        for (int kk = 0; kk < 4; ++kk) {
            short8 bfr = *(const short8*)&Bs[t * 16 + l16][kk * 32 + quad * 8];
            acc = __builtin_amdgcn_mfma_f32_16x16x32_bf16(af[kk], bfr, acc, 0, 0, 0);
        }
        #pragma unroll
        for (int r = 0; r < 4; ++r) {
            int gr = row0 + quad * 4 + r;
            // chunk-major: chunk = t>>1, col-in-chunk = (t&1)*16 + l16
            Cb[(size_t)(t >> 1) * n * 32 + (size_t)gr * 32 + (t & 1) * 16 + l16]
                = f2bf(acc[r] * dv[r]);
        }
    }
}

// ---------------- chunked gather-aggregate ----------------
// One dispatch per 32-feature chunk. hc/zc/biasc are pre-offset to the chunk.
// Quarter-wave (16 lanes) per node row (64B). Gather set = n*64B = 3.2MB
// -> L2-resident within a pass. 8 rows in flight per quarter.

template<bool FINAL>
__global__ __launch_bounds__(256) void aggregate_chunk(
    const unsigned int* __restrict__ hc,      // [n][16] uints (this chunk)
    const unsigned short* __restrict__ ell,
    const int* __restrict__ cnt, const float* __restrict__ biasc,
    unsigned int* __restrict__ zc,            // !FINAL: [n][16] uints
    float* __restrict__ outc,                 // FINAL: row stride 64 fp32
    int n)
{
    const int q = threadIdx.x >> 4, l16 = threadIdx.x & 15;
    const int node = blockIdx.x * 16 + q;
    if (node >= n) return;
    int deg = cnt[node];
    const float d = rsqrtf((float)deg + 1.0f);
    if (deg > ELL_CAP) deg = ELL_CAP;
    const unsigned short* __restrict__ row = ell + (size_t)node * ELL_CAP;

    float2 acc = bfunpack(hc[(size_t)node * 16 + l16]);   // self term (scaled h)
    int e = 0;
    for (; e + 8 <= deg; e += 8) {
        uint4 w = *(const uint4*)&row[e];
        int s0 = w.x & 0xffff, s1 = w.x >> 16;
        int s2 = w.y & 0xffff, s3 = w.y >> 16;
        int s4 = w.z & 0xffff, s5 = w.z >> 16;
        int s6 = w.w & 0xffff, s7 = w.w >> 16;
        float2 v0 = bfunpack(hc[(size_t)s0 * 16 + l16]);
        float2 v1 = bfunpack(hc[(size_t)s1 * 16 + l16]);
        float2 v2 = bfunpack(hc[(size_t)s2 * 16 + l16]);
        float2 v3 = bfunpack(hc[(size_t)s3 * 16 + l16]);
        float2 v4 = bfunpack(hc[(size_t)s4 * 16 + l16]);
        float2 v5 = bfunpack(hc[(size_t)s5 * 16 + l16]);
        float2 v6 = bfunpack(hc[(size_t)s6 * 16 + l16]);
        float2 v7 = bfunpack(hc[(size_t)s7 * 16 + l16]);
        acc.x += ((v0.x + v1.x) + (v2.x + v3.x)) + ((v4.x + v5.x) + (v6.x + v7.x));
        acc.y += ((v0.y + v1.y) + (v2.y + v3.y)) + ((v4.y + v5.y) + (v6.y + v7.y));
    }
    for (; e + 4 <= deg; e += 4) {
        uint2 w = *(const uint2*)&row[e];
        int s0 = w.x & 0xffff, s1 = w.x >> 16;
        int s2 = w.y & 0xffff, s3 = w.y >> 16;
        float2 v0 = bfunpack(hc[(size_t)s0 * 16 + l16]);
        float2 v1 = bfunpack(hc[(size_t)s1 * 16 + l16]);
        float2 v2 = bfunpack(hc[(size_t)s2 * 16 + l16]);
        float2 v3 = bfunpack(hc[(size_t)s3 * 16 + l16]);
        acc.x += (v0.x + v1.x) + (v2.x + v3.x);
        acc.y += (v0.y + v1.y) + (v2.y + v3.y);
    }
    for (; e < deg; ++e) {
        float2 v = bfunpack(hc[(size_t)row[e] * 16 + l16]);
        acc.x += v.x; acc.y += v.y;
    }

    float2 b = *(const float2*)(biasc + l16 * 2);
    if (FINAL) {
        float2 o;
        o.x = fmaf(acc.x, d, b.x);
        o.y = fmaf(acc.y, d, b.y);
        ((float2*)outc)[(size_t)node * 32 + l16] = o;   // stride 64 fp32 = 32 float2
    } else {
        float ox = fmaxf(fmaf(acc.x, d, b.x), 0.f);
        float oy = fmaxf(fmaf(acc.y, d, b.y), 0.f);
        zc[(size_t)node * 16 + l16] =
            (unsigned int)f2bf(ox) | ((unsigned int)f2bf(oy) << 16);
    }
}

// ---------------- launcher ----------------

extern "C" void kernel_launch(void* const* d_in, const int* in_sizes, int n_in,
                              void* d_out, int out_size, void* d_ws, size_t ws_size,
                              hipStream_t stream)
{
    const float* x  = (const float*)d_in[0];
    const int*   ei = (const int*)d_in[1];   // [2][E] int32
    const float* W1 = (const float*)d_in[2];
    const float* b1 = (const float*)d_in[3];
    const float* W2 = (const float*)d_in[4];
    const float* b2 = (const float*)d_in[5];
    float* out = (float*)d_out;

    const int N = in_sizes[0] / 128;   // 50000
    const int E = in_sizes[1] / 2;     // 800000
    const int* src = ei;
    const int* dst = ei + E;
    const int partSize = (N + NPART - 1) / NPART;   // 6250

    char* ws = (char*)d_ws;
    size_t off = 0;
    auto alloc = [&](size_t bytes) -> void* {
        void* p = ws + off;
        off += (bytes + 255) & ~(size_t)255;
        return p;
    };
    int*            cnt  = (int*)           alloc((size_t)N * 4);
    unsigned short* ell  = (unsigned short*)alloc((size_t)N * ELL_CAP * 2);
    short*          w1t  = (short*)         alloc((size_t)128 * 128 * 2);
    short*          w2t  = (short*)         alloc((size_t)64 * 128 * 2);
    unsigned short* h1c  = (unsigned short*)alloc((size_t)N * 128 * 2);  // [4][N][32] bf16
    unsigned int*   z1c  = (unsigned int*)  alloc((size_t)N * 64 * 4);   // [4][N][16] bf16x2
    unsigned short* h2c  = (unsigned short*)alloc((size_t)N * 64 * 2);   // [2][N][32] bf16

    init_misc<<<(N + 255) / 256, 256, 0, stream>>>(W1, W2, w1t, w2t, cnt, N);
    build_ell_part<<<256 * NPART, 256, 0, stream>>>(src, dst, cnt, ell, E, partSize);

    // layer 1: gemm (scaled, chunk-major) then 4 chunked aggregate passes
    gemm_mfma<128, true><<<(N + 63) / 64, 256, 0, stream>>>(x, w1t, cnt, h1c, N);
    const int aggBlocks = (N + 15) / 16;   // 3125
    for (int c = 0; c < 4; ++c) {
        aggregate_chunk<false><<<aggBlocks, 256, 0, stream>>>(
            (const unsigned int*)h1c + (size_t)c * N * 16, ell, cnt,
            b1 + c * 32, z1c + (size_t)c * N * 16, nullptr, N);
    }

    // layer 2: gemm (chunked A, scaled, chunk-major C) then 2 passes
    gemm_mfma<64, false><<<(N + 63) / 64, 256, 0, stream>>>(z1c, w2t, cnt, h2c, N);
    for (int c = 0; c < 2; ++c) {
        aggregate_chunk<true><<<aggBlocks, 256, 0, stream>>>(
            (const unsigned int*)h2c + (size_t)c * N * 16, ell, cnt,
            b2 + c * 32, nullptr, out + c * 32, N);
    }
}

// Round 4
// 198.556 us; speedup vs baseline: 1.0654x; 1.0654x over previous
//
#include <hip/hip_runtime.h>
#include <hip/hip_bf16.h>

// 2-layer GCN on MI355X.
// R8 post-mortem: L2-residency chunking = NULL (195->211.5; extra dispatches
// + max-deg divergence). Combined with R6 (8-deep MLP = null): the ~2.4 TB/s
// gather plateau is NOT latency- or MLP-bound -> per-instruction fixed cost
// of scattered vector loads (one gather instr per edge in every prior scheme).
// R9: wide gathers. One dwordx4 instr serves 4 edges (L1: 16 lanes x 16B per
// 256B row) / 8 edges (L2: 8 lanes x 16B per 128B row). Per-lane fp32
// partials; shfl_xor butterfly folds quads/octs once per node. Gather instrs:
// 800K->200K (L1), 400K->100K (L2). Misses/bytes unchanged -> clean
// discriminator for instr-rate vs miss-rate bound. Structure otherwise = R6
// (row-major scaled h, standalone build, 7 dispatches incl. memset).

#define ELL_CAP 64   // deg ~ Poisson(16); P(deg>=64) ~ 1e-18
#define NPART 8      // = XCD count

typedef __attribute__((ext_vector_type(8))) short short8;   // 8 bf16 (4 VGPRs)
typedef __attribute__((ext_vector_type(4))) float f32x4;

static __device__ __forceinline__ unsigned short f2bf(float f) {
    unsigned int u = __float_as_uint(f);
    u = (u + 0x7fff + ((u >> 16) & 1)) >> 16;   // round-to-nearest-even
    return (unsigned short)u;
}
static __device__ __forceinline__ float2 bfunpack(unsigned int u) {
    return make_float2(__uint_as_float(u << 16),            // low short  = feat 2i
                       __uint_as_float(u & 0xffff0000u));   // high short = feat 2i+1
}

// ---------------- weight transposes (cnt zeroed by hipMemsetAsync) ---------

__global__ void convert_weights(const float* __restrict__ W1, const float* __restrict__ W2,
                                short* __restrict__ w1t, short* __restrict__ w2t)
{
    int i = blockIdx.x * blockDim.x + threadIdx.x;
    if (i < 128 * 128) {
        int k = i >> 7, nn = i & 127;
        w1t[nn * 128 + k] = (short)f2bf(W1[i]);
    } else if (i < 128 * 128 + 128 * 64) {
        int j = i - 128 * 128;
        int k = j >> 6, nn = j & 63;
        w2t[nn * 128 + k] = (short)f2bf(W2[j]);
    }
}

// ---------------- XCD-partitioned ELL build (R6 version) -------------------

__global__ __launch_bounds__(256) void build_ell_part(
    const int* __restrict__ src, const int* __restrict__ dst,
    int* __restrict__ cnt, unsigned short* __restrict__ ell, int E, int partSize)
{
    const int part   = blockIdx.x & (NPART - 1);   // = XCD under round-robin
    const int chunk  = blockIdx.x >> 3;
    const int nchunk = gridDim.x >> 3;
    const int lo = part * partSize, hi = lo + partSize;

    const int  E4  = E >> 2;
    const int  per = (E4 + nchunk - 1) / nchunk;
    const int  i1  = min((chunk + 1) * per, E4);
    const int4* __restrict__ d4p = (const int4*)dst;
    const int4* __restrict__ s4p = (const int4*)src;

    for (int i = chunk * per + threadIdx.x; i < i1; i += 256) {
        int4 d4 = d4p[i];
        int4 s4 = s4p[i];
        if (d4.x >= lo && d4.x < hi) {
            int p = atomicAdd(&cnt[d4.x], 1);
            if (p < ELL_CAP) ell[(size_t)d4.x * ELL_CAP + p] = (unsigned short)s4.x;
        }
        if (d4.y >= lo && d4.y < hi) {
            int p = atomicAdd(&cnt[d4.y], 1);
            if (p < ELL_CAP) ell[(size_t)d4.y * ELL_CAP + p] = (unsigned short)s4.y;
        }
        if (d4.z >= lo && d4.z < hi) {
            int p = atomicAdd(&cnt[d4.z], 1);
            if (p < ELL_CAP) ell[(size_t)d4.z * ELL_CAP + p] = (unsigned short)s4.z;
        }
        if (d4.w >= lo && d4.w < hi) {
            int p = atomicAdd(&cnt[d4.w], 1);
            if (p < ELL_CAP) ell[(size_t)d4.w * ELL_CAP + p] = (unsigned short)s4.w;
        }
    }
    if (chunk == 0) {                              // E % 4 tail
        for (int e = (E & ~3) + threadIdx.x; e < E; e += 256) {
            int d = dst[e];
            if (d >= lo && d < hi) {
                int p = atomicAdd(&cnt[d], 1);
                if (p < ELL_CAP) ell[(size_t)d * ELL_CAP + p] = (unsigned short)src[e];
            }
        }
    }
}

// ---------------- MFMA GEMM: Cb[i][j] = bf16(dinv[i]*(A W)[i][j]), row-major

template<int NC, bool AF32>
__global__ __launch_bounds__(256) void gemm_mfma(
    const void* __restrict__ Av, const short* __restrict__ Bt,
    const int* __restrict__ cnt, unsigned short* __restrict__ Cb, int n)
{
    __shared__ short Bs[NC][136];
    const int tid = threadIdx.x;

    #pragma unroll
    for (int i = 0; i < NC / 16; ++i) {      // NC*128 shorts, 16B per thread/iter
        int idx = tid + i * 256;
        int nrow = idx >> 4;
        int kcol = (idx & 15) * 8;
        *(short8*)&Bs[nrow][kcol] = *(const short8*)(Bt + nrow * 128 + kcol);
    }
    __syncthreads();

    const int wave = tid >> 6, lane = tid & 63;
    const int row0 = blockIdx.x * 64 + wave * 16;
    if (row0 >= n) return;
    const int quad = lane >> 4, l16 = lane & 15;

    short8 af[4];
    if (AF32) {
        const float* arow = (const float*)Av + (size_t)(row0 + l16) * 128 + quad * 8;
        #pragma unroll
        for (int kk = 0; kk < 4; ++kk) {
            float4 u = *(const float4*)(arow + kk * 32);
            float4 v = *(const float4*)(arow + kk * 32 + 4);
            short8 f;
            f[0] = (short)f2bf(u.x); f[1] = (short)f2bf(u.y);
            f[2] = (short)f2bf(u.z); f[3] = (short)f2bf(u.w);
            f[4] = (short)f2bf(v.x); f[5] = (short)f2bf(v.y);
            f[6] = (short)f2bf(v.z); f[7] = (short)f2bf(v.w);
            af[kk] = f;
        }
    } else {
        const short* arow = (const short*)Av + (size_t)(row0 + l16) * 128 + quad * 8;
        #pragma unroll
        for (int kk = 0; kk < 4; ++kk)
            af[kk] = *(const short8*)(arow + kk * 32);
    }

    float dv[4];
    #pragma unroll
    for (int r = 0; r < 4; ++r)
        dv[r] = rsqrtf((float)cnt[row0 + quad * 4 + r] + 1.0f);

    #pragma unroll
    for (int t = 0; t < NC / 16; ++t) {
        f32x4 acc = {0.f, 0.f, 0.f, 0.f};
        #pragma unroll
        for (int kk = 0; kk < 4; ++kk) {
            short8 bfr = *(const short8*)&Bs[t * 16 + l16][kk * 32 + quad * 8];
            acc = __builtin_amdgcn_mfma_f32_16x16x32_bf16(af[kk], bfr, acc, 0, 0, 0);
        }
        #pragma unroll
        for (int r = 0; r < 4; ++r) {
            int gr = row0 + quad * 4 + r;
            Cb[(size_t)gr * NC + t * 16 + l16] = f2bf(acc[r] * dv[r]);
        }
    }
}

// ---------------- wide-gather aggregates ----------------
// L1: one wave per node, 256B rows. One dwordx4 gather instr = 4 edges
// (quad q handles edge e+q, lanes l16 fetch 16B each). Per-lane 8 fp32
// partials; 2-round shfl_xor butterfly (bits 4,5) folds quads at the end.
// Padded ELL slots hold poison -> index clamped, value zeroed via cndmask
// (NOT multiply: poison bf16 may be NaN).

__global__ __launch_bounds__(256) void aggregate_l1(
    const unsigned short* __restrict__ hb,   // [n][128] bf16, dinv-scaled
    const unsigned short* __restrict__ ell,
    const int* __restrict__ cnt, const float* __restrict__ bias,
    unsigned int* __restrict__ z1b, int n)   // [n][64] bf16x2
{
    const int node = blockIdx.x * 4 + (threadIdx.x >> 6);
    if (node >= n) return;
    const int lane = threadIdx.x & 63;
    const int quad = lane >> 4, l16 = lane & 15;

    int deg = cnt[node];
    const float d = rsqrtf((float)deg + 1.0f);
    if (deg > ELL_CAP) deg = ELL_CAP;
    const unsigned short* __restrict__ row = ell + (size_t)node * ELL_CAP;

    float acc[8];
    {   // self term: counted once (quad 0 only)
        uint4 v = *(const uint4*)(hb + (size_t)node * 128 + l16 * 8);
        bool val = (quad == 0);
        #pragma unroll
        for (int j = 0; j < 4; ++j) {
            float2 f = bfunpack(((const unsigned int*)&v)[j]);
            acc[2 * j]     = val ? f.x : 0.f;
            acc[2 * j + 1] = val ? f.y : 0.f;
        }
    }
    const int degR = (deg + 3) & ~3;
    #pragma unroll 2
    for (int e = 0; e < degR; e += 4) {
        unsigned int w0 = *(const unsigned int*)&row[e];       // edges e,e+1
        unsigned int w1 = *(const unsigned int*)&row[e + 2];   // edges e+2,e+3
        unsigned int hw = (quad & 2) ? w1 : w0;
        int s = (quad & 1) ? (int)(hw >> 16) : (int)(hw & 0xffff);
        s = min(s, n - 1);                                      // poison-safe
        uint4 v = *(const uint4*)(hb + (size_t)s * 128 + l16 * 8);
        bool val = (e + quad < deg);
        #pragma unroll
        for (int j = 0; j < 4; ++j) {
            float2 f = bfunpack(((const unsigned int*)&v)[j]);
            acc[2 * j]     += val ? f.x : 0.f;
            acc[2 * j + 1] += val ? f.y : 0.f;
        }
    }
    #pragma unroll
    for (int j = 0; j < 8; ++j) {            // fold 4 quads
        acc[j] += __shfl_xor(acc[j], 16);
        acc[j] += __shfl_xor(acc[j], 32);
    }
    if (quad == 0) {
        unsigned int ow[4];
        #pragma unroll
        for (int j = 0; j < 4; ++j) {
            float bx = bias[l16 * 8 + 2 * j];
            float by = bias[l16 * 8 + 2 * j + 1];
            float ox = fmaxf(fmaf(acc[2 * j],     d, bx), 0.f);
            float oy = fmaxf(fmaf(acc[2 * j + 1], d, by), 0.f);
            ow[j] = (unsigned int)f2bf(ox) | ((unsigned int)f2bf(oy) << 16);
        }
        *(uint4*)&z1b[(size_t)node * 64 + l16 * 4] = *(const uint4*)ow;
    }
}

// L2: one wave per node, 128B rows. One dwordx4 gather instr = 8 edges
// (oct o handles edge e+o, lanes l8 fetch 16B each). 3-round butterfly.

__global__ __launch_bounds__(256) void aggregate_l2(
    const unsigned short* __restrict__ hb,   // [n][64] bf16, dinv-scaled
    const unsigned short* __restrict__ ell,
    const int* __restrict__ cnt, const float* __restrict__ bias,
    float* __restrict__ out, int n)          // [n][64] fp32
{
    const int node = blockIdx.x * 4 + (threadIdx.x >> 6);
    if (node >= n) return;
    const int lane = threadIdx.x & 63;
    const int oct = lane >> 3, l8 = lane & 7;

    int deg = cnt[node];
    const float d = rsqrtf((float)deg + 1.0f);
    if (deg > ELL_CAP) deg = ELL_CAP;
    const unsigned short* __restrict__ row = ell + (size_t)node * ELL_CAP;

    float acc[8];
    {   // self term (oct 0 only)
        uint4 v = *(const uint4*)(hb + (size_t)node * 64 + l8 * 8);
        bool val = (oct == 0);
        #pragma unroll
        for (int j = 0; j < 4; ++j) {
            float2 f = bfunpack(((const unsigned int*)&v)[j]);
            acc[2 * j]     = val ? f.x : 0.f;
            acc[2 * j + 1] = val ? f.y : 0.f;
        }
    }
    const int degR = (deg + 7) & ~7;
    #pragma unroll 2
    for (int e = 0; e < degR; e += 8) {
        uint4 w = *(const uint4*)&row[e];    // edges e..e+7
        unsigned int pw = (oct & 4) ? ((oct & 2) ? w.w : w.z)
                                    : ((oct & 2) ? w.y : w.x);
        int s = (oct & 1) ? (int)(pw >> 16) : (int)(pw & 0xffff);
        s = min(s, n - 1);                   // poison-safe
        uint4 v = *(const uint4*)(hb + (size_t)s * 64 + l8 * 8);
        bool val = (e + oct < deg);
        #pragma unroll
        for (int j = 0; j < 4; ++j) {
            float2 f = bfunpack(((const unsigned int*)&v)[j]);
            acc[2 * j]     += val ? f.x : 0.f;
            acc[2 * j + 1] += val ? f.y : 0.f;
        }
    }
    #pragma unroll
    for (int j = 0; j < 8; ++j) {            // fold 8 octs
        acc[j] += __shfl_xor(acc[j], 8);
        acc[j] += __shfl_xor(acc[j], 16);
        acc[j] += __shfl_xor(acc[j], 32);
    }
    if (oct == 0) {
        float* op = out + (size_t)node * 64 + l8 * 8;
        float4 o0, o1;
        o0.x = fmaf(acc[0], d, bias[l8 * 8 + 0]);
        o0.y = fmaf(acc[1], d, bias[l8 * 8 + 1]);
        o0.z = fmaf(acc[2], d, bias[l8 * 8 + 2]);
        o0.w = fmaf(acc[3], d, bias[l8 * 8 + 3]);
        o1.x = fmaf(acc[4], d, bias[l8 * 8 + 4]);
        o1.y = fmaf(acc[5], d, bias[l8 * 8 + 5]);
        o1.z = fmaf(acc[6], d, bias[l8 * 8 + 6]);
        o1.w = fmaf(acc[7], d, bias[l8 * 8 + 7]);
        *(float4*)(op)     = o0;
        *(float4*)(op + 4) = o1;
    }
}

// ---------------- launcher ----------------

extern "C" void kernel_launch(void* const* d_in, const int* in_sizes, int n_in,
                              void* d_out, int out_size, void* d_ws, size_t ws_size,
                              hipStream_t stream)
{
    const float* x  = (const float*)d_in[0];
    const int*   ei = (const int*)d_in[1];   // [2][E] int32
    const float* W1 = (const float*)d_in[2];
    const float* b1 = (const float*)d_in[3];
    const float* W2 = (const float*)d_in[4];
    const float* b2 = (const float*)d_in[5];
    float* out = (float*)d_out;

    const int N = in_sizes[0] / 128;   // 50000
    const int E = in_sizes[1] / 2;     // 800000
    const int* src = ei;
    const int* dst = ei + E;
    const int partSize = (N + NPART - 1) / NPART;   // 6250

    char* ws = (char*)d_ws;
    size_t off = 0;
    auto alloc = [&](size_t bytes) -> void* {
        void* p = ws + off;
        off += (bytes + 255) & ~(size_t)255;
        return p;
    };
    int*            cnt  = (int*)           alloc((size_t)N * 4);
    unsigned short* ell  = (unsigned short*)alloc((size_t)N * ELL_CAP * 2);
    short*          w1t  = (short*)         alloc((size_t)128 * 128 * 2);
    short*          w2t  = (short*)         alloc((size_t)64 * 128 * 2);
    unsigned short* h1b  = (unsigned short*)alloc((size_t)N * 128 * 2);  // bf16
    unsigned int*   z1b  = (unsigned int*)  alloc((size_t)N * 64 * 4);   // bf16x2
    unsigned short* h2b  = (unsigned short*)alloc((size_t)N * 64 * 2);   // bf16

    hipMemsetAsync(cnt, 0, (size_t)N * 4, stream);
    convert_weights<<<(128 * 192 + 255) / 256, 256, 0, stream>>>(W1, W2, w1t, w2t);
    build_ell_part<<<256 * NPART, 256, 0, stream>>>(src, dst, cnt, ell, E, partSize);

    // layer 1
    gemm_mfma<128, true><<<(N + 63) / 64, 256, 0, stream>>>(x, w1t, cnt, h1b, N);
    aggregate_l1<<<(N + 3) / 4, 256, 0, stream>>>(h1b, ell, cnt, b1, z1b, N);

    // layer 2
    gemm_mfma<64, false><<<(N + 63) / 64, 256, 0, stream>>>(z1b, w2t, cnt, h2b, N);
    aggregate_l2<<<(N + 3) / 4, 256, 0, stream>>>(h2b, ell, cnt, b2, out, N);
}